// Round 5
// baseline (230.334 us; speedup 1.0000x reference)
//
#include <hip/hip_runtime.h>

#define NH   8192
#define DIM  256
#define NTOT 16384
#define TILE 256
#define NB   64                   // NTOT / TILE
#define NTRI (NB * (NB + 1) / 2)  // 2080
#define TRIOFF(x) ((x) * (2 * NB + 1 - (x)) / 2)  // x*(129-x)/2

constexpr float GAMMA = 0.00390625f; // 1/256

using short8  = __attribute__((ext_vector_type(8))) short;
using short4v = __attribute__((ext_vector_type(4))) short;
using f32x4   = __attribute__((ext_vector_type(4))) float;

__device__ __forceinline__ unsigned short bf16_rne(float f) {
    unsigned u = __float_as_uint(f);
    u += 0x7FFFu + ((u >> 16) & 1u);
    return (unsigned short)(u >> 16);
}

// ---------------- fused split (fp32 -> bf16 hi/lo) + row norms ----------------
__global__ void prep_kernel(const float* __restrict__ zs,
                            const float* __restrict__ zt,
                            unsigned short* __restrict__ Zh,
                            unsigned short* __restrict__ Zl,
                            float* __restrict__ n2) {
    int w = threadIdx.x >> 6, l = threadIdx.x & 63;
    int row = blockIdx.x * 4 + w;
    const float* zp = (row < NH) ? zs + (size_t)row * DIM
                                 : zt + (size_t)(row - NH) * DIM;
    float4 v = *(const float4*)(zp + l * 4);
    float s = v.x * v.x + v.y * v.y + v.z * v.z + v.w * v.w;
#pragma unroll
    for (int off = 32; off; off >>= 1) s += __shfl_xor(s, off);
    if (l == 0) n2[row] = s;

    float x[4] = {v.x, v.y, v.z, v.w};
    short4v hv, lv;
#pragma unroll
    for (int j = 0; j < 4; ++j) {
        unsigned short h = bf16_rne(x[j]);
        float hf = __uint_as_float((unsigned)h << 16);
        hv[j] = (short)h;
        lv[j] = (short)bf16_rne(x[j] - hf);
    }
    *(short4v*)(Zh + (size_t)row * DIM + l * 4) = hv;
    *(short4v*)(Zl + (size_t)row * DIM + l * 4) = lv;
}

// ---------------- main: 256x256 tiles, 8 waves, 16x16x32 MFMA ----------------
// phase-split schedule, raw s_barrier + counted vmcnt (T3+T4), dbuf LDS
__global__ __launch_bounds__(512, 2)
void mmd_mfma_kernel(const unsigned short* __restrict__ Zh,
                     const unsigned short* __restrict__ Zl,
                     const float* __restrict__ n2,
                     double* __restrict__ partial) {
    // 2 buffers x {Ah, Al, Bh, Bl} x 256 rows x 32 cols bf16 = 131072 B
    __shared__ __align__(16) unsigned short lds[2][4][8192];

    const int tid = threadIdx.x;
    const int w = tid >> 6, l = tid & 63;
    const int wr = w >> 2, wc = w & 3;   // 2 x 4 wave grid; wave owns 128x64
    const int fr = l & 15;               // fragment row/col within 16
    const int g  = l >> 4;               // k-group 0..3

    // XCD-aware bijective swizzle (2080 % 8 == 0 -> chunked remap is exact)
    int t = ((int)blockIdx.x & 7) * (NTRI / 8) + ((int)blockIdx.x >> 3);

    // linear t -> upper-triangle (r, c), r <= c
    int r = (int)((129.0 - sqrt(129.0 * 129.0 - 8.0 * (double)t)) * 0.5);
    if (r < 0) r = 0;
    if (r > NB - 1) r = NB - 1;
    while (r < NB - 1 && TRIOFF(r + 1) <= t) ++r;
    while (r > 0 && TRIOFF(r) > t) --r;
    const int c = r + (t - TRIOFF(r));
    const int xbase = r * TILE, ybase = c * TILE;

    const unsigned short* gAh = Zh + (size_t)xbase * DIM;
    const unsigned short* gAl = Zl + (size_t)xbase * DIM;
    const unsigned short* gBh = Zh + (size_t)ybase * DIM;
    const unsigned short* gBl = Zl + (size_t)ybase * DIM;

    // swizzled 16B-slot for fragment reads: slot' = g ^ ((fr>>1)&3)  (R2/R3: 0 conflicts)
    const int slotp = g ^ ((fr >> 1) & 3);
    const int aoff = (wr * 128 + fr) * 32 + slotp * 8; // shorts; + m*512
    const int boff = (wc * 64  + fr) * 32 + slotp * 8; // shorts; + n*512

    // staging geometry: thread covers 16B at linear offset q*8192 + tid*16 per array
    const int srow0 = tid >> 2;                            // row (q=0); q=1 adds 128
    const int sslot = (tid & 3) ^ ((srow0 >> 1) & 3);      // pre-swizzled source slot
    const int scol  = sslot * 8;                           // element col within chunk
    const unsigned dsto = (unsigned)tid * 8;               // shorts; + q*4096

    f32x4 acc[8][4];
#pragma unroll
    for (int m = 0; m < 8; ++m)
#pragma unroll
        for (int n = 0; n < 4; ++n) acc[m][n] = {0.f, 0.f, 0.f, 0.f};

#define STAGE(KC, P)                                                               \
    {                                                                              \
        _Pragma("unroll")                                                          \
        for (int q = 0; q < 2; ++q) {                                              \
            const int rw = q * 128 + srow0;                                        \
            const size_t go = (size_t)rw * DIM + (KC) + scol;                      \
            unsigned short* d0 = (unsigned short*)&lds[P][0][q * 4096 + dsto];     \
            unsigned short* d1 = (unsigned short*)&lds[P][1][q * 4096 + dsto];     \
            unsigned short* d2 = (unsigned short*)&lds[P][2][q * 4096 + dsto];     \
            unsigned short* d3 = (unsigned short*)&lds[P][3][q * 4096 + dsto];     \
            __builtin_amdgcn_global_load_lds(gAh + go, d0, 16, 0, 0);              \
            __builtin_amdgcn_global_load_lds(gAl + go, d1, 16, 0, 0);              \
            __builtin_amdgcn_global_load_lds(gBh + go, d2, 16, 0, 0);              \
            __builtin_amdgcn_global_load_lds(gBl + go, d3, 16, 0, 0);              \
        }                                                                          \
    }

// one phase: ds_read A m-pair -> barrier -> 24 MFMA -> barrier
#define MPAIR(Mlo)                                                                              \
    {                                                                                           \
        short8 ah0 = *(const short8*)&A_h[aoff + (Mlo) * 512];                                  \
        short8 al0 = *(const short8*)&A_l[aoff + (Mlo) * 512];                                  \
        short8 ah1 = *(const short8*)&A_h[aoff + ((Mlo) + 1) * 512];                            \
        short8 al1 = *(const short8*)&A_l[aoff + ((Mlo) + 1) * 512];                            \
        __builtin_amdgcn_s_barrier();                                                           \
        __builtin_amdgcn_s_setprio(1);                                                          \
        _Pragma("unroll")                                                                       \
        for (int n = 0; n < 4; ++n) {                                                           \
            acc[(Mlo)][n]     = __builtin_amdgcn_mfma_f32_16x16x32_bf16(ah0, bh[n], acc[(Mlo)][n], 0, 0, 0);     \
            acc[(Mlo)][n]     = __builtin_amdgcn_mfma_f32_16x16x32_bf16(ah0, bl[n], acc[(Mlo)][n], 0, 0, 0);     \
            acc[(Mlo)][n]     = __builtin_amdgcn_mfma_f32_16x16x32_bf16(al0, bh[n], acc[(Mlo)][n], 0, 0, 0);     \
            acc[(Mlo) + 1][n] = __builtin_amdgcn_mfma_f32_16x16x32_bf16(ah1, bh[n], acc[(Mlo) + 1][n], 0, 0, 0); \
            acc[(Mlo) + 1][n] = __builtin_amdgcn_mfma_f32_16x16x32_bf16(ah1, bl[n], acc[(Mlo) + 1][n], 0, 0, 0); \
            acc[(Mlo) + 1][n] = __builtin_amdgcn_mfma_f32_16x16x32_bf16(al1, bh[n], acc[(Mlo) + 1][n], 0, 0, 0); \
        }                                                                                       \
        __builtin_amdgcn_s_setprio(0);                                                          \
        __builtin_amdgcn_s_barrier();                                                           \
    }

    STAGE(0, 0);  // chunk 0 -> buffer 0; waited inside loop (ch=0 path)

    for (int ch = 0; ch < 8; ++ch) {
        const int p = ch & 1;
        if (ch < 7) {
            STAGE((ch + 1) * 32, p ^ 1);  // chunk ch+1 in flight across this whole chunk
            asm volatile("s_waitcnt vmcnt(8)" ::: "memory");  // wait only chunk ch's 8
        } else {
            asm volatile("s_waitcnt vmcnt(0)" ::: "memory");  // last chunk: nothing younger
        }
        __builtin_amdgcn_s_barrier();  // all waves' chunk-ch stages landed

        const unsigned short* A_h = lds[p][0];
        const unsigned short* A_l = lds[p][1];
        const unsigned short* B_h = lds[p][2];
        const unsigned short* B_l = lds[p][3];

        // phase 0 reads include all B fragments
        short8 bh[4], bl[4];
#pragma unroll
        for (int n = 0; n < 4; ++n) {
            bh[n] = *(const short8*)&B_h[boff + n * 512];
            bl[n] = *(const short8*)&B_l[boff + n * 512];
        }
        MPAIR(0)
        MPAIR(2)
        MPAIR(4)
        MPAIR(6)
        // trailing phase barrier doubles as end-of-chunk fence:
        // next iteration's STAGE overwrites lds[p] only after all waves read it.
    }

    // epilogue: d2 = |x|^2 + |y|^2 - 2 x.y, exp, sum
    // C/D layout: col = lane&15 (fr), row = (lane>>4)*4 + reg  (verified R2/R3, absmax 0.0)
    float yn[4];
#pragma unroll
    for (int n = 0; n < 4; ++n) yn[n] = n2[ybase + wc * 64 + n * 16 + fr];
    float fsum = 0.0f;
#pragma unroll
    for (int m = 0; m < 8; ++m) {
#pragma unroll
        for (int j = 0; j < 4; ++j) {
            float xn = n2[xbase + wr * 128 + m * 16 + g * 4 + j];
#pragma unroll
            for (int n = 0; n < 4; ++n) {
                float d2 = xn + yn[n] - 2.0f * acc[m][n][j];
                d2 = fmaxf(d2, 0.0f);
                fsum += __expf(-GAMMA * d2);
            }
        }
    }

#pragma unroll
    for (int off = 32; off; off >>= 1) fsum += __shfl_xor(fsum, off);

    __syncthreads();  // full sync before LDS reuse for reduction
    double* wsum = (double*)&lds[0][0][0];
    if (l == 0) wsum[w] = (double)fsum;
    __syncthreads();
    if (tid == 0) {
        double tot = 0.0;
#pragma unroll
        for (int i = 0; i < 8; ++i) tot += wsum[i];
        double wgt = ((xbase < NH) == (ybase < NH)) ? 1.0 : -1.0;
        if (r != c) wgt *= 2.0; // off-diagonal tiles counted twice (symmetry)
        partial[blockIdx.x] = wgt * tot;
    }
}

// ---------------- final reduce ----------------
__global__ void reduce_partials_kernel(const double* __restrict__ partial,
                                       float* __restrict__ out) {
    __shared__ double ws[4];
    double s = 0.0;
    for (int i = threadIdx.x; i < NTRI; i += 256) s += partial[i];
#pragma unroll
    for (int off = 32; off; off >>= 1) s += __shfl_xor(s, off);
    if ((threadIdx.x & 63) == 0) ws[threadIdx.x >> 6] = s;
    __syncthreads();
    if (threadIdx.x == 0) {
        double tot = ws[0] + ws[1] + ws[2] + ws[3];
        out[0] = (float)(tot / ((double)NH * (double)NH));
    }
}

extern "C" void kernel_launch(void* const* d_in, const int* in_sizes, int n_in,
                              void* d_out, int out_size, void* d_ws, size_t ws_size,
                              hipStream_t stream) {
    const float* zs = (const float*)d_in[0];
    const float* zt = (const float*)d_in[1];
    float* out = (float*)d_out;

    unsigned short* Zh = (unsigned short*)d_ws;                      // 8 MB
    unsigned short* Zl = (unsigned short*)((char*)d_ws + 8388608);   // 8 MB
    float*  n2      = (float*)((char*)d_ws + 16777216);              // 64 KB
    double* partial = (double*)((char*)d_ws + 16842752);             // 16.6 KB

    prep_kernel<<<NTOT / 4, 256, 0, stream>>>(zs, zt, Zh, Zl, n2);
    mmd_mfma_kernel<<<NTRI, 512, 0, stream>>>(Zh, Zl, n2, partial);
    reduce_partials_kernel<<<1, 256, 0, stream>>>(partial, out);
}

// Round 6
// 112.832 us; speedup vs baseline: 2.0414x; 2.0414x over previous
//
#include <hip/hip_runtime.h>

#define NH   8192
#define DIM  256
#define NTOT 16384
#define TM   256                  // tile rows
#define TN   128                  // tile cols
#define NRB  64                   // row blocks
#define NCB  128                  // col blocks
// kept tiles: C >= 2R (not entirely below diagonal); count/R = 128-2R
// F(R) = R*(129-R); total = F(64) = 4160
#define NTILES 4160
#define FCUM(R) ((R) * (129 - (R)))

constexpr float GAMMA = 0.00390625f; // 1/256

using short4v = __attribute__((ext_vector_type(4))) short;
using half8   = __attribute__((ext_vector_type(8))) _Float16;
using f32x4   = __attribute__((ext_vector_type(4))) float;

// ---------------- fused convert (fp32 -> f16) + exact fp32 row norms ----------------
__global__ void prep_kernel(const float* __restrict__ zs,
                            const float* __restrict__ zt,
                            unsigned short* __restrict__ Zf,
                            float* __restrict__ n2) {
    int w = threadIdx.x >> 6, l = threadIdx.x & 63;
    int row = blockIdx.x * 4 + w;
    const float* zp = (row < NH) ? zs + (size_t)row * DIM
                                 : zt + (size_t)(row - NH) * DIM;
    float4 v = *(const float4*)(zp + l * 4);
    float s = v.x * v.x + v.y * v.y + v.z * v.z + v.w * v.w;
#pragma unroll
    for (int off = 32; off; off >>= 1) s += __shfl_xor(s, off);
    if (l == 0) n2[row] = s;

    float x[4] = {v.x, v.y, v.z, v.w};
    short4v hv;
#pragma unroll
    for (int j = 0; j < 4; ++j) {
        _Float16 h = (_Float16)x[j];          // RNE
        hv[j] = *(short*)&h;
    }
    *(short4v*)(Zf + (size_t)row * DIM + l * 4) = hv;
}

// ---------------- main: 256x128 tiles, 4 waves, f16 single-MFMA, dbuf LDS ----------------
__global__ __launch_bounds__(256, 2)
void mmd_mfma_kernel(const unsigned short* __restrict__ Zf,
                     const float* __restrict__ n2,
                     double* __restrict__ partial) {
    // 2 buffers x {A 256x32, B 128x32} f16 = 2 x 12288 halves = 48 KB
    __shared__ __align__(16) unsigned short lds[2][12288];

    const int tid = threadIdx.x;
    const int w = tid >> 6, l = tid & 63;
    const int wr = w >> 1, wc = w & 1;   // 2x2 wave grid; wave owns 128x64
    const int fr = l & 15;               // fragment row/col within 16
    const int g  = l >> 4;               // k-group 0..3

    // XCD-aware bijective swizzle (4160 % 8 == 0)
    int t = ((int)blockIdx.x & 7) * (NTILES / 8) + ((int)blockIdx.x >> 3);

    // t -> (R, C): largest R with F(R) <= t ; C = 2R + (t - F(R))
    int R = (int)((129.0 - sqrt(129.0 * 129.0 - 4.0 * (double)t)) * 0.5);
    if (R < 0) R = 0;
    if (R > NRB - 1) R = NRB - 1;
    while (R < NRB - 1 && FCUM(R + 1) <= t) ++R;
    while (R > 0 && FCUM(R) > t) --R;
    const int C = 2 * R + (t - FCUM(R));
    const int xbase = R * TM, ybase = C * TN;
    const bool straddle = (C <= 2 * R + 1);  // tile touches/crosses the diagonal

    const unsigned short* gA = Zf + (size_t)xbase * DIM;
    const unsigned short* gB = Zf + (size_t)ybase * DIM;

    // fragment reads: slot' = g ^ ((fr>>1)&3)   (verified conflict-free R2/R3)
    const int slotp = g ^ ((fr >> 1) & 3);
    const int aoff = (wr * 128 + fr) * 32 + slotp * 8;          // + m*512
    const int boff = 8192 + (wc * 64 + fr) * 32 + slotp * 8;    // + n*512

    f32x4 acc[8][4];
#pragma unroll
    for (int m = 0; m < 8; ++m)
#pragma unroll
        for (int n = 0; n < 4; ++n) acc[m][n] = {0.f, 0.f, 0.f, 0.f};

    // staging: linear LDS dest (tid*16B), pre-swizzled global source slot
#define STAGE(KC, P)                                                                 \
    {                                                                                \
        _Pragma("unroll")                                                            \
        for (int q = 0; q < 4; ++q) { /* A: 1024 x 16B */                            \
            const int idx = q * 256 + tid;                                           \
            const int row = idx >> 2;                                                \
            const int slot = (idx & 3) ^ ((row >> 1) & 3);                           \
            const unsigned short* src = gA + (size_t)row * DIM + (KC) + slot * 8;    \
            __builtin_amdgcn_global_load_lds(src, &lds[P][idx * 8], 16, 0, 0);       \
        }                                                                            \
        _Pragma("unroll")                                                            \
        for (int q = 0; q < 2; ++q) { /* B: 512 x 16B */                             \
            const int idx = q * 256 + tid;                                           \
            const int row = idx >> 2;                                                \
            const int slot = (idx & 3) ^ ((row >> 1) & 3);                           \
            const unsigned short* src = gB + (size_t)row * DIM + (KC) + slot * 8;    \
            __builtin_amdgcn_global_load_lds(src, &lds[P][8192 + idx * 8], 16, 0, 0);\
        }                                                                            \
    }

    STAGE(0, 0);
    __syncthreads();

    for (int ch = 0; ch < 8; ++ch) {
        const int p = ch & 1;
        if (ch < 7) STAGE((ch + 1) * 32, p ^ 1);

        half8 bq[4];
#pragma unroll
        for (int n = 0; n < 4; ++n) bq[n] = *(const half8*)&lds[p][boff + n * 512];
        __builtin_amdgcn_s_setprio(1);
#pragma unroll
        for (int m = 0; m < 8; ++m) {
            half8 aq = *(const half8*)&lds[p][aoff + m * 512];
#pragma unroll
            for (int n = 0; n < 4; ++n)
                acc[m][n] = __builtin_amdgcn_mfma_f32_16x16x32_f16(aq, bq[n], acc[m][n], 0, 0, 0);
        }
        __builtin_amdgcn_s_setprio(0);
        __syncthreads();  // reads of lds[p] done; stage into lds[p^1] drained
    }

    // epilogue: d2 = |x|^2 + |y|^2 - 2 x.y, exp, weighted sum
    // C/D layout: col = lane&15 (fr), row = (lane>>4)*4 + reg   (verified R2/R3)
    float yn[4];
    int   gjs[4];
#pragma unroll
    for (int n = 0; n < 4; ++n) {
        gjs[n] = ybase + wc * 64 + n * 16 + fr;
        yn[n]  = n2[gjs[n]];
    }
    float fsum = 0.0f;
    if (!straddle) {  // entire tile strictly above diagonal: uniform weight 2
#pragma unroll
        for (int m = 0; m < 8; ++m) {
#pragma unroll
            for (int j = 0; j < 4; ++j) {
                float xn = n2[xbase + wr * 128 + m * 16 + g * 4 + j];
#pragma unroll
                for (int n = 0; n < 4; ++n) {
                    float d2 = xn + yn[n] - 2.0f * acc[m][n][j];
                    d2 = fmaxf(d2, 0.0f);
                    fsum += __expf(-GAMMA * d2);
                }
            }
        }
        fsum *= 2.0f;
    } else {  // per-element triangle weight: i<j -> 2, i==j -> 1, i>j -> 0
#pragma unroll
        for (int m = 0; m < 8; ++m) {
#pragma unroll
            for (int j = 0; j < 4; ++j) {
                const int gi = xbase + wr * 128 + m * 16 + g * 4 + j;
                float xn = n2[gi];
#pragma unroll
                for (int n = 0; n < 4; ++n) {
                    float d2 = xn + yn[n] - 2.0f * acc[m][n][j];
                    d2 = fmaxf(d2, 0.0f);
                    float e = __expf(-GAMMA * d2);
                    float wgt = (gi < gjs[n]) ? 2.0f : ((gi == gjs[n]) ? 1.0f : 0.0f);
                    fsum += wgt * e;
                }
            }
        }
    }

#pragma unroll
    for (int off = 32; off; off >>= 1) fsum += __shfl_xor(fsum, off);

    __syncthreads();
    double* wsum = (double*)&lds[0][0];
    if (l == 0) wsum[w] = (double)fsum;
    __syncthreads();
    if (tid == 0) {
        double tot = wsum[0] + wsum[1] + wsum[2] + wsum[3];
        // sign: same half -> +, cross -> -  (tiles never straddle the s/t boundary)
        double sgn = ((xbase < NH) == (ybase < NH)) ? 1.0 : -1.0;
        partial[blockIdx.x] = sgn * tot;
    }
}

// ---------------- final reduce ----------------
__global__ void reduce_partials_kernel(const double* __restrict__ partial,
                                       float* __restrict__ out) {
    __shared__ double ws[4];
    double s = 0.0;
    for (int i = threadIdx.x; i < NTILES; i += 256) s += partial[i];
#pragma unroll
    for (int off = 32; off; off >>= 1) s += __shfl_xor(s, off);
    if ((threadIdx.x & 63) == 0) ws[threadIdx.x >> 6] = s;
    __syncthreads();
    if (threadIdx.x == 0) {
        double tot = ws[0] + ws[1] + ws[2] + ws[3];
        out[0] = (float)(tot / ((double)NH * (double)NH));
    }
}

extern "C" void kernel_launch(void* const* d_in, const int* in_sizes, int n_in,
                              void* d_out, int out_size, void* d_ws, size_t ws_size,
                              hipStream_t stream) {
    const float* zs = (const float*)d_in[0];
    const float* zt = (const float*)d_in[1];
    float* out = (float*)d_out;

    unsigned short* Zf = (unsigned short*)d_ws;                  // 8 MB (f16)
    float*  n2      = (float*)((char*)d_ws + 8388608);           // 64 KB
    double* partial = (double*)((char*)d_ws + 8454144);          // 33 KB

    prep_kernel<<<NTOT / 4, 256, 0, stream>>>(zs, zt, Zf, n2);
    mmd_mfma_kernel<<<NTILES, 256, 0, stream>>>(Zf, n2, partial);
    reduce_partials_kernel<<<1, 256, 0, stream>>>(partial, out);
}